// Round 4
// baseline (3115.374 us; speedup 1.0000x reference)
//
#include <hip/hip_runtime.h>

#define Hh 1024
#define NBATCH 128
#define TSTEPS 256
#define DOUT 1024
#define SLOT (NBATCH * Hh)

typedef _Float16 half8 __attribute__((ext_vector_type(8)));
typedef _Float16 half4v __attribute__((ext_vector_type(4)));
typedef float floatx4 __attribute__((ext_vector_type(4)));

// Raw barriers: BAR_LGKM drains only LDS (keeps prefetch loads in flight);
// BAR_ONLY is a pure rendezvous (poll gate). __syncthreads() is used where a
// full vmcnt(0) drain is REQUIRED (h-stores before flag publish).
#define BAR_LGKM() asm volatile("s_waitcnt lgkmcnt(0)\n\ts_barrier" ::: "memory")
#define BAR_ONLY() asm volatile("s_barrier" ::: "memory")

__device__ __forceinline__ float fast_sigmoid(float x) {
  float e = __expf(-x);
  return __builtin_amdgcn_rcpf(1.0f + e);
}
__device__ __forceinline__ float fast_tanh(float x) {
  x = fminf(15.0f, fmaxf(-15.0f, x));
  float e = __expf(-2.0f * x);
  return 1.0f - 2.0f * e * __builtin_amdgcn_rcpf(1.0f + e);
}

__global__ void prep_kernel(const float* __restrict__ W_ih, const float* __restrict__ W_hh,
                            const float* __restrict__ W_fc, const float* __restrict__ b_ih,
                            const float* __restrict__ b_hh, const float* __restrict__ hT,
                            _Float16* __restrict__ w_ih_h, _Float16* __restrict__ w_sum_h,
                            _Float16* __restrict__ w_fc_h, float* __restrict__ b_sum,
                            _Float16* __restrict__ hs0, int* __restrict__ flags) {
  int i0 = blockIdx.x * blockDim.x + threadIdx.x;
  int stride = gridDim.x * blockDim.x;
  for (int i = i0; i < 4096 * 1024; i += stride) {
    float a = W_ih[i];
    w_ih_h[i] = (_Float16)a;
    w_sum_h[i] = (_Float16)(a + W_hh[i]);
  }
  for (int i = i0; i < 1024 * 1024; i += stride) w_fc_h[i] = (_Float16)W_fc[i];
  for (int i = i0; i < 4096; i += stride) b_sum[i] = b_ih[i] + b_hh[i];
  for (int i = i0; i < NBATCH * Hh; i += stride) hs0[i] = (_Float16)hT[i];
  for (int i = i0; i < 512; i += stride) flags[i] = 0;
}

// Fused persistent kernel, 256 WGs x 4 waves.
// WGs 0..127: LSTM. (g=wg>>6, jb=wg&63) owns j-cols [16jb,16jb+16) of all 4
// gates for bands 4g..4g+3 (16 batch rows each; rows are independent chains).
// Per step the WG round-robins the 4 bands; depth-1 prefetch: at the end of
// tick (t,bi) it polls band bi+1 (flags set 3 ticks ago -> instant) and
// issues that band's A-loads so the MALL latency overlaps the next tick.
// All h-ring reads in the steady loop are AGENT-scope atomic u64 loads
// (sc1 -> MALL-direct, immune to any L1/L2 staleness); h-stores are the
// R2-proven per-lane 16-bit AGENT-scope stores (write-through).
// WGs 128..255: FC, consuming slots as flags arrive (plain cold loads).
__global__ __launch_bounds__(256, 1) void fused_kernel(
    const _Float16* __restrict__ w_ih_h, const _Float16* __restrict__ w_sum_h,
    const _Float16* __restrict__ w_fc_h, const float* __restrict__ b_sum,
    const float* __restrict__ b_fc, _Float16* __restrict__ hs,
    int* __restrict__ flags, float* __restrict__ out) {
  const int wg = blockIdx.x;
  const int tid = threadIdx.x;
  const int wave = tid >> 6;
  const int lane = tid & 63;
  const int l15 = lane & 15;
  const int quad = lane >> 4;
  const int kbase = wave * 256;

  __shared__ float part[4][4][4][64];  // [srcwave][tile/gate][reg][lane] = 16KB

  if (wg < 128) {
    // ---------------- LSTM role ----------------
    const int g = wg >> 6;
    const int jb = wg & 63;
    const int j0 = jb * 16;

    float bias[4];
#pragma unroll
    for (int gt = 0; gt < 4; ++gt) bias[gt] = b_sum[gt * 1024 + j0 + l15];

    half8 B[4][8];
    float cst[4] = {0.f, 0.f, 0.f, 0.f};
    unsigned long long qa[8], qb[8];  // prefetched A fragment (one band-tick)

    auto load_B = [&](const _Float16* w) {
#pragma unroll
      for (int gt = 0; gt < 4; ++gt) {
        const _Float16* rp = w + (size_t)(gt * 1024 + j0 + l15) * Hh + kbase + quad * 8;
#pragma unroll
        for (int ks = 0; ks < 8; ++ks) B[gt][ks] = *(const half8*)(rp + ks * 32);
      }
    };

    auto aptr = [&](int t, int bi) {
      return hs + (size_t)t * SLOT + (size_t)(64 * g + 16 * bi + l15) * Hh + kbase + quad * 8;
    };

    // issue 16 atomic u64 loads (no wait; compiler tracks vmcnt to first use)
    auto issue_A = [&](const _Float16* ap) {
#pragma unroll
      for (int ks = 0; ks < 8; ++ks) {
        qa[ks] = __hip_atomic_load((const unsigned long long*)(ap + ks * 32),
                                   __ATOMIC_RELAXED, __HIP_MEMORY_SCOPE_AGENT);
        qb[ks] = __hip_atomic_load((const unsigned long long*)(ap + ks * 32 + 4),
                                   __ATOMIC_RELAXED, __HIP_MEMORY_SCOPE_AGENT);
      }
    };

    // reduce + elementwise + h-store + flag publish for tick (t, bi)
    auto tail = [&](int bi, int t, floatx4 acc[4]) {
#pragma unroll
      for (int gt = 0; gt < 4; ++gt)
#pragma unroll
        for (int r = 0; r < 4; ++r) part[wave][gt][r][lane] = acc[gt][r];
      BAR_LGKM();  // LDS-only barrier: prefetch loads stay in flight

      float gv[4];
#pragma unroll
      for (int gt = 0; gt < 4; ++gt) {
        float s = bias[gt];
#pragma unroll
        for (int src = 0; src < 4; ++src) s += part[src][gt][wave][lane];
        gv[gt] = s;
      }
      float ig = fast_sigmoid(gv[0]);
      float fg = fast_sigmoid(gv[1]);
      float gg = fast_tanh(gv[2]);
      float og = fast_sigmoid(gv[3]);
      float c = fg * cst[bi] + ig * gg;
      cst[bi] = c;
      float h = og * fast_tanh(c);

      int row = 64 * g + 16 * bi + quad * 4 + wave;
      _Float16 hv = (_Float16)h;
      unsigned short ub;
      __builtin_memcpy(&ub, &hv, 2);
      __hip_atomic_store(
          (unsigned short*)(hs + (size_t)(t + 1) * SLOT + (size_t)row * Hh + j0 + l15),
          ub, __ATOMIC_RELAXED, __HIP_MEMORY_SCOPE_AGENT);
      // Full drain: at this point only h-stores are outstanding (prefetch for
      // the next tick has not been issued yet), so vmcnt(0) costs nothing.
      __syncthreads();
      if (tid == 0)
        __hip_atomic_store(&flags[(4 * g + bi) * 64 + jb], t + 1,
                           __ATOMIC_RELAXED, __HIP_MEMORY_SCOPE_AGENT);
    };

    // poll band bi for slot t (self-flag substituted), gate, issue prefetch
    auto poll_gate_issue = [&](int bi, int t) {
      if (wave == 0) {
        const int* fp = &flags[(4 * g + bi) * 64];
        while (1) {
          int v = (lane == jb) ? t
                               : __hip_atomic_load(&fp[lane], __ATOMIC_RELAXED,
                                                   __HIP_MEMORY_SCOPE_AGENT);
          if (__all(v >= t)) break;
          __builtin_amdgcn_s_sleep(1);
        }
      }
      BAR_ONLY();  // control-only gate: no data crosses, no drain needed
      issue_A(aptr(t, bi));
    };

    // ---- step 0: x = hT (slot 0, safe via kernel boundary), plain loads ----
    load_B(w_ih_h);
#pragma unroll
    for (int bi = 0; bi < 4; ++bi) {
      floatx4 acc[4] = {};
      const _Float16* ap = aptr(0, bi);
#pragma unroll
      for (int ks = 0; ks < 8; ++ks) {
        half8 a = *(const half8*)(ap + ks * 32);
#pragma unroll
        for (int gt = 0; gt < 4; ++gt)
          acc[gt] = __builtin_amdgcn_mfma_f32_16x16x32_f16(a, B[gt][ks], acc[gt], 0, 0, 0);
      }
      tail(bi, 0, acc);
    }

    // ---- steps 1..255: x = hx = h, W_sum; 4-band rotation w/ prefetch ----
    load_B(w_sum_h);
    poll_gate_issue(0, 1);  // prime

    for (int t = 1; t < TSTEPS; ++t) {
#pragma unroll
      for (int bi = 0; bi < 4; ++bi) {
        floatx4 acc[4] = {};
#pragma unroll
        for (int ks = 0; ks < 8; ++ks) {
          union { unsigned long long u; half4v h; } x, y;
          x.u = qa[ks];
          y.u = qb[ks];
          half8 a = __builtin_shufflevector(x.h, y.h, 0, 1, 2, 3, 4, 5, 6, 7);
#pragma unroll
          for (int gt = 0; gt < 4; ++gt)
            acc[gt] = __builtin_amdgcn_mfma_f32_16x16x32_f16(a, B[gt][ks], acc[gt], 0, 0, 0);
        }
        tail(bi, t, acc);
        if (bi < 3) {
          poll_gate_issue(bi + 1, t);
        } else if (t < TSTEPS - 1) {
          poll_gate_issue(0, t + 1);
        }
      }
    }
  } else {
    // ---------------- FC role ----------------
    const int f = wg - 128;
    const int g = f >> 6;
    const int jb = f & 63;
    const int d0 = jb * 16;

    half8 Bf[8];
    {
      const _Float16* rp = w_fc_h + (size_t)(d0 + l15) * Hh + kbase + quad * 8;
#pragma unroll
      for (int ks = 0; ks < 8; ++ks) Bf[ks] = *(const half8*)(rp + ks * 32);
    }
    float bv = b_fc[d0 + l15];

    for (int t = 1; t <= TSTEPS; ++t) {
      {
        const int* fp = &flags[(4 * g + wave) * 64];
        while (1) {
          int v = __hip_atomic_load(&fp[lane], __ATOMIC_RELAXED,
                                    __HIP_MEMORY_SCOPE_AGENT);
          if (__all(v >= t)) break;
          __builtin_amdgcn_s_sleep(1);
        }
      }
      __syncthreads();

      floatx4 acc[4] = {};
      const _Float16* base = hs + (size_t)t * SLOT;
#pragma unroll
      for (int mt = 0; mt < 4; ++mt) {
        const _Float16* ap = base + (size_t)(64 * g + 16 * mt + l15) * Hh + kbase + quad * 8;
#pragma unroll
        for (int ks = 0; ks < 8; ++ks) {
          half8 a = *(const half8*)(ap + ks * 32);
          acc[mt] = __builtin_amdgcn_mfma_f32_16x16x32_f16(a, Bf[ks], acc[mt], 0, 0, 0);
        }
      }
#pragma unroll
      for (int mt = 0; mt < 4; ++mt)
#pragma unroll
        for (int r = 0; r < 4; ++r) part[wave][mt][r][lane] = acc[mt][r];
      __syncthreads();

#pragma unroll
      for (int mt = 0; mt < 4; ++mt) {
        float s = bv;
#pragma unroll
        for (int src = 0; src < 4; ++src) s += part[src][mt][wave][lane];
        int row = 64 * g + 16 * mt + quad * 4 + wave;
        out[((size_t)row * TSTEPS + (t - 1)) * DOUT + d0 + l15] = s;
      }
      __syncthreads();
    }
  }
}

extern "C" void kernel_launch(void* const* d_in, const int* in_sizes, int n_in,
                              void* d_out, int out_size, void* d_ws, size_t ws_size,
                              hipStream_t stream) {
  const float* hT   = (const float*)d_in[0];
  const float* W_ih = (const float*)d_in[1];
  const float* W_hh = (const float*)d_in[2];
  const float* b_ih = (const float*)d_in[3];
  const float* b_hh = (const float*)d_in[4];
  const float* W_fc = (const float*)d_in[5];
  const float* b_fc = (const float*)d_in[6];
  float* out = (float*)d_out;

  char* ws = (char*)d_ws;
  int* flags        = (int*)ws;                         // 2KB (8 bands x 64)
  float* b_sum      = (float*)(ws + 4096);              // 16KB
  _Float16* w_ih_h  = (_Float16*)(ws + 65536);          // 8MB
  _Float16* w_sum_h = w_ih_h + (size_t)4096 * 1024;     // 8MB
  _Float16* w_fc_h  = w_sum_h + (size_t)4096 * 1024;    // 2MB
  _Float16* hs      = w_fc_h + (size_t)1024 * 1024;     // 257 * 256KB = 67.3MB

  prep_kernel<<<4096, 256, 0, stream>>>(W_ih, W_hh, W_fc, b_ih, b_hh, hT,
                                        w_ih_h, w_sum_h, w_fc_h, b_sum, hs, flags);
  fused_kernel<<<256, 256, 0, stream>>>(w_ih_h, w_sum_h, w_fc_h, b_sum, b_fc,
                                        hs, flags, out);
}

// Round 5
// 2520.690 us; speedup vs baseline: 1.2359x; 1.2359x over previous
//
#include <hip/hip_runtime.h>

#define Hh 1024
#define NBATCH 128
#define TSTEPS 256
#define DOUT 1024
#define SLOT (NBATCH * Hh)

typedef _Float16 half8 __attribute__((ext_vector_type(8)));
typedef float floatx4 __attribute__((ext_vector_type(4)));

// LDS-only barrier (keeps global loads/stores in flight across it).
#define BAR_LGKM() asm volatile("s_waitcnt lgkmcnt(0)\n\ts_barrier" ::: "memory")
// Wave-local full VM drain (stores ~1 tick old at call sites -> nearly free).
#define VMFENCE() asm volatile("s_waitcnt vmcnt(0)" ::: "memory")
// Compiler scheduling fence (no hoisting loads above the flag check).
#define SCHED_FENCE() asm volatile("" ::: "memory")

__device__ __forceinline__ float fast_sigmoid(float x) {
  float e = __expf(-x);
  return __builtin_amdgcn_rcpf(1.0f + e);
}
__device__ __forceinline__ float fast_tanh(float x) {
  x = fminf(15.0f, fmaxf(-15.0f, x));
  float e = __expf(-2.0f * x);
  return 1.0f - 2.0f * e * __builtin_amdgcn_rcpf(1.0f + e);
}

__global__ void prep_kernel(const float* __restrict__ W_ih, const float* __restrict__ W_hh,
                            const float* __restrict__ W_fc, const float* __restrict__ b_ih,
                            const float* __restrict__ b_hh, const float* __restrict__ hT,
                            _Float16* __restrict__ w_ih_h, _Float16* __restrict__ w_sum_h,
                            _Float16* __restrict__ w_fc_h, float* __restrict__ b_sum,
                            _Float16* __restrict__ hs0, int* __restrict__ flags) {
  int i0 = blockIdx.x * blockDim.x + threadIdx.x;
  int stride = gridDim.x * blockDim.x;
  for (int i = i0; i < 4096 * 1024; i += stride) {
    float a = W_ih[i];
    w_ih_h[i] = (_Float16)a;
    w_sum_h[i] = (_Float16)(a + W_hh[i]);
  }
  for (int i = i0; i < 1024 * 1024; i += stride) w_fc_h[i] = (_Float16)W_fc[i];
  for (int i = i0; i < 4096; i += stride) b_sum[i] = b_ih[i] + b_hh[i];
  for (int i = i0; i < NBATCH * Hh; i += stride) hs0[i] = (_Float16)hT[i];
  for (int i = i0; i < 2048; i += stride) flags[i] = 0;
}

// Fused persistent kernel, 256 WGs x 4 waves.
//
// LSTM WGs 0..127: (g=wg>>6, jb=wg&63) owns j-cols [16jb,16jb+16) of all 4
// gates for bands 4g..4g+3 (16 rows each), rotating one band per tick.
// Per-tick pipeline (everything latency-bearing is one tick ahead):
//   MFMA (A in regs, prefetched last tick)
//   publish flag for stores issued LAST tick (vmcnt(0) ~free, per-wave flag)
//   check register-resident flag loads (issued last tick; expected pass)
//   issue A-prefetch for next tick (plain dwordx4; gap ~= rest of tick)
//   issue flag loads for tick after next
//   partials -> LDS[parity], BAR_LGKM (the ONE barrier), reduce, elementwise,
//   issue h-stores (16-bit agent write-through, R2-proven), end tick.
// Flags: flags[band*256 + jb*4 + wave] = s  <=>  wave's rows of (band,jb)
// slot s are visible at the coherence point. Check reads all 4 waves' flags
// for 64 jb via two u64 agent-atomic loads per lane.
// FC WGs 128..255: consume slots as flags arrive (R4-proven body).
__global__ __launch_bounds__(256, 1) void fused_kernel(
    const _Float16* __restrict__ w_ih_h, const _Float16* __restrict__ w_sum_h,
    const _Float16* __restrict__ w_fc_h, const float* __restrict__ b_sum,
    const float* __restrict__ b_fc, _Float16* __restrict__ hs,
    int* __restrict__ flags, float* __restrict__ out) {
  const int wg = blockIdx.x;
  const int tid = threadIdx.x;
  const int wave = tid >> 6;
  const int lane = tid & 63;
  const int l15 = lane & 15;
  const int quad = lane >> 4;
  const int kbase = wave * 256;

  __shared__ float part[2][4][4][4][64];  // [parity][srcwave][gate][reg][lane] = 32KB

  if (wg < 128) {
    // ---------------- LSTM role ----------------
    const int g = wg >> 6;
    const int jb = wg & 63;
    const int j0 = jb * 16;
    int* fbase = flags + (4 * g) * 256;  // band b array at fbase + b*256

    float bias[4];
#pragma unroll
    for (int gt = 0; gt < 4; ++gt) bias[gt] = b_sum[gt * 1024 + j0 + l15];

    half8 B[4][8];
    float cst[4] = {0.f, 0.f, 0.f, 0.f};
    half8 Abuf[2][8];              // double-buffered prefetched A fragment
    unsigned long long fl[2][2];   // double-buffered pre-issued flag loads

    auto load_B = [&](const _Float16* w) {
#pragma unroll
      for (int gt = 0; gt < 4; ++gt) {
        const _Float16* rp = w + (size_t)(gt * 1024 + j0 + l15) * Hh + kbase + quad * 8;
#pragma unroll
        for (int ks = 0; ks < 8; ++ks) B[gt][ks] = *(const half8*)(rp + ks * 32);
      }
    };

    auto aptr = [&](int t, int b) {
      return hs + (size_t)t * SLOT + (size_t)(64 * g + 16 * b + l15) * Hh + kbase + quad * 8;
    };

    auto mfma_all = [&](const half8* a, floatx4 acc[4]) {
#pragma unroll
      for (int ks = 0; ks < 8; ++ks)
#pragma unroll
        for (int gt = 0; gt < 4; ++gt)
          acc[gt] = __builtin_amdgcn_mfma_f32_16x16x32_f16(a[ks], B[gt][ks], acc[gt], 0, 0, 0);
    };

    // Publish per-wave flag for stores issued LAST tick. vmcnt(0) drains only
    // ops that are ~1 tick old (this tick's prefetch not yet issued) -> ~free.
    auto publish = [&](int band, int val) {
      VMFENCE();
      if (lane == 0)
        __hip_atomic_store(&fbase[band * 256 + jb * 4 + wave], val,
                           __ATOMIC_RELAXED, __HIP_MEMORY_SCOPE_AGENT);
    };

    auto issue_flags = [&](int band, unsigned long long* dst) {
      const unsigned long long* p =
          (const unsigned long long*)&fbase[band * 256 + lane * 4];
      dst[0] = __hip_atomic_load(p, __ATOMIC_RELAXED, __HIP_MEMORY_SCOPE_AGENT);
      dst[1] = __hip_atomic_load(p + 1, __ATOMIC_RELAXED, __HIP_MEMORY_SCOPE_AGENT);
    };

    auto check = [&](int band, int T, unsigned long long f0, unsigned long long f1) {
      int a0 = (int)f0, a1 = (int)(f0 >> 32), a2 = (int)f1, a3 = (int)(f1 >> 32);
      int mn = a0 < a1 ? a0 : a1;
      int mn2 = a2 < a3 ? a2 : a3;
      mn = mn < mn2 ? mn : mn2;
      if (!__all((int)(mn >= T))) {
        const unsigned long long* p =
            (const unsigned long long*)&fbase[band * 256 + lane * 4];
        while (1) {
          unsigned long long g0 =
              __hip_atomic_load(p, __ATOMIC_RELAXED, __HIP_MEMORY_SCOPE_AGENT);
          unsigned long long g1 =
              __hip_atomic_load(p + 1, __ATOMIC_RELAXED, __HIP_MEMORY_SCOPE_AGENT);
          int b0 = (int)g0, b1 = (int)(g0 >> 32), b2 = (int)g1, b3 = (int)(g1 >> 32);
          int m = b0 < b1 ? b0 : b1;
          int m2 = b2 < b3 ? b2 : b3;
          m = m < m2 ? m : m2;
          if (__all((int)(m >= T))) break;
          __builtin_amdgcn_s_sleep(1);
        }
      }
      SCHED_FENCE();  // A-prefetch below must not be hoisted above this
    };

    // reduce + elementwise + h-store issue (NO drain, NO second barrier)
    auto tail = [&](int b, int slotOut, floatx4 acc[4], int parity) {
#pragma unroll
      for (int gt = 0; gt < 4; ++gt)
#pragma unroll
        for (int r = 0; r < 4; ++r) part[parity][wave][gt][r][lane] = acc[gt][r];
      BAR_LGKM();
      float gv[4];
#pragma unroll
      for (int gt = 0; gt < 4; ++gt) {
        float s = bias[gt];
#pragma unroll
        for (int src = 0; src < 4; ++src) s += part[parity][src][gt][wave][lane];
        gv[gt] = s;
      }
      float ig = fast_sigmoid(gv[0]);
      float fg = fast_sigmoid(gv[1]);
      float gg = fast_tanh(gv[2]);
      float og = fast_sigmoid(gv[3]);
      float c = fg * cst[b] + ig * gg;
      cst[b] = c;
      float h = og * fast_tanh(c);
      int row = 64 * g + 16 * b + quad * 4 + wave;
      _Float16 hv = (_Float16)h;
      unsigned short ub;
      __builtin_memcpy(&ub, &hv, 2);
      __hip_atomic_store(
          (unsigned short*)(hs + (size_t)slotOut * SLOT + (size_t)row * Hh + j0 + l15),
          ub, __ATOMIC_RELAXED, __HIP_MEMORY_SCOPE_AGENT);
    };

    // ---- prologue: t=0, x=hT (slot 0), W_ih, plain per-tick loads ----
    load_B(w_ih_h);
#pragma unroll
    for (int b = 0; b < 4; ++b) {
      half8 a[8];
      const _Float16* ap = aptr(0, b);
#pragma unroll
      for (int ks = 0; ks < 8; ++ks) a[ks] = *(const half8*)(ap + ks * 32);
      floatx4 acc[4] = {};
      mfma_all(a, acc);
      if (b > 0) publish(b - 1, 1);
      tail(b, 1, acc, b & 1);
      if (b == 2) issue_flags(0, fl[1]);
      if (b == 3) {
        check(0, 1, fl[1][0], fl[1][1]);
        const _Float16* pp = aptr(1, 0);
#pragma unroll
        for (int ks = 0; ks < 8; ++ks) Abuf[0][ks] = *(const half8*)(pp + ks * 32);
        issue_flags(1, fl[0]);
      }
    }
    load_B(w_sum_h);

    // ---- steady: t=1..255, x=hx=h, W_sum ----
    for (int t = 1; t < TSTEPS; ++t) {
#pragma unroll
      for (int b = 0; b < 4; ++b) {
        const int cur = b & 1, nxt = cur ^ 1;
        floatx4 acc[4] = {};
        mfma_all(Abuf[cur], acc);
        publish((b + 3) & 3, (b == 0) ? t : t + 1);
        const bool last = (t == TSTEPS - 1) && (b == 3);
        if (!last) {
          const int cb = (b + 1) & 3;
          const int T = (b < 3) ? t : t + 1;
          check(cb, T, fl[cur][0], fl[cur][1]);
          const _Float16* pp = (b < 3) ? aptr(t, b + 1) : aptr(t + 1, 0);
#pragma unroll
          for (int ks = 0; ks < 8; ++ks) Abuf[nxt][ks] = *(const half8*)(pp + ks * 32);
          issue_flags((b + 2) & 3, fl[nxt]);
        }
        tail(b, t + 1, acc, cur);
      }
    }
    publish(3, TSTEPS);  // final band-3 flag (stores from tick (255,3))
  } else {
    // ---------------- FC role ----------------
    const int f = wg - 128;
    const int g = f >> 6;
    const int jb = f & 63;
    const int d0 = jb * 16;
    int* fbase = flags + (4 * g) * 256;

    half8 Bf[8];
    {
      const _Float16* rp = w_fc_h + (size_t)(d0 + l15) * Hh + kbase + quad * 8;
#pragma unroll
      for (int ks = 0; ks < 8; ++ks) Bf[ks] = *(const half8*)(rp + ks * 32);
    }
    float bv = b_fc[d0 + l15];

    for (int t = 1; t <= TSTEPS; ++t) {
      {  // wave w waits for band w (all 64 jb x 4 waves)
        const unsigned long long* p =
            (const unsigned long long*)&fbase[wave * 256 + lane * 4];
        while (1) {
          unsigned long long g0 =
              __hip_atomic_load(p, __ATOMIC_RELAXED, __HIP_MEMORY_SCOPE_AGENT);
          unsigned long long g1 =
              __hip_atomic_load(p + 1, __ATOMIC_RELAXED, __HIP_MEMORY_SCOPE_AGENT);
          int b0 = (int)g0, b1 = (int)(g0 >> 32), b2 = (int)g1, b3 = (int)(g1 >> 32);
          int m = b0 < b1 ? b0 : b1;
          int m2 = b2 < b3 ? b2 : b3;
          m = m < m2 ? m : m2;
          if (__all((int)(m >= t))) break;
          __builtin_amdgcn_s_sleep(1);
        }
      }
      __syncthreads();

      floatx4 acc[4] = {};
      const _Float16* base = hs + (size_t)t * SLOT;
#pragma unroll
      for (int mt = 0; mt < 4; ++mt) {
        const _Float16* ap = base + (size_t)(64 * g + 16 * mt + l15) * Hh + kbase + quad * 8;
#pragma unroll
        for (int ks = 0; ks < 8; ++ks) {
          half8 a = *(const half8*)(ap + ks * 32);
          acc[mt] = __builtin_amdgcn_mfma_f32_16x16x32_f16(a, Bf[ks], acc[mt], 0, 0, 0);
        }
      }
#pragma unroll
      for (int mt = 0; mt < 4; ++mt)
#pragma unroll
        for (int r = 0; r < 4; ++r) part[0][wave][mt][r][lane] = acc[mt][r];
      __syncthreads();

#pragma unroll
      for (int mt = 0; mt < 4; ++mt) {
        float s = bv;
#pragma unroll
        for (int src = 0; src < 4; ++src) s += part[0][src][mt][wave][lane];
        int row = 64 * g + 16 * mt + quad * 4 + wave;
        out[((size_t)row * TSTEPS + (t - 1)) * DOUT + d0 + l15] = s;
      }
      __syncthreads();
    }
  }
}

extern "C" void kernel_launch(void* const* d_in, const int* in_sizes, int n_in,
                              void* d_out, int out_size, void* d_ws, size_t ws_size,
                              hipStream_t stream) {
  const float* hT   = (const float*)d_in[0];
  const float* W_ih = (const float*)d_in[1];
  const float* W_hh = (const float*)d_in[2];
  const float* b_ih = (const float*)d_in[3];
  const float* b_hh = (const float*)d_in[4];
  const float* W_fc = (const float*)d_in[5];
  const float* b_fc = (const float*)d_in[6];
  float* out = (float*)d_out;

  char* ws = (char*)d_ws;
  int* flags        = (int*)ws;                         // 8KB (8 bands x 64 jb x 4 waves)
  float* b_sum      = (float*)(ws + 16384);             // 16KB
  _Float16* w_ih_h  = (_Float16*)(ws + 65536);          // 8MB
  _Float16* w_sum_h = w_ih_h + (size_t)4096 * 1024;     // 8MB
  _Float16* w_fc_h  = w_sum_h + (size_t)4096 * 1024;    // 2MB
  _Float16* hs      = w_fc_h + (size_t)1024 * 1024;     // 257 * 256KB = 67.3MB

  prep_kernel<<<4096, 256, 0, stream>>>(W_ih, W_hh, W_fc, b_ih, b_hh, hT,
                                        w_ih_h, w_sum_h, w_fc_h, b_sum, hs, flags);
  fused_kernel<<<256, 256, 0, stream>>>(w_ih_h, w_sum_h, w_fc_h, b_sum, b_fc,
                                        hs, flags, out);
}